// Round 1
// baseline (95.805 us; speedup 1.0000x reference)
//
#include <hip/hip_runtime.h>

#define NB 128
#define NS 8192
#define NC 256                // chunks per sequence (32-step chunks; was 128x64)
#define NCP 16                // combined matrices per sequence (one per block)
#define NL (NS / NC)          // 32 steps per chunk
#define M4 (NL / 4)           // 8 float4 groups

#define LOG2E 1.4426950408889634f
#define HLOG2PI 0.918938533204672742f
#define LN2 0.69314718055994531f

// LDS matrix layout: R-only units (halved vs r13's dual R+T) so 6-8 blocks/CU
// fit. Transposed operand in combine is read strided (8-way broadcast float2
// reads -> conflict-free). mx scale lives in row-0 pad (col 16).
#define ROWS 20          // padded leading dim
#define UNIT 320         // one unit: R[16x20]

typedef float v2f __attribute__((ext_vector_type(2)));

__device__ __forceinline__ float fexp2(float x) { return __builtin_amdgcn_exp2f(x); }
__device__ __forceinline__ float flog2(float x) { return __builtin_amdgcn_logf(x); }

__device__ __forceinline__ float gsum16(float v) {
    v += __shfl_xor(v, 1, 16);
    v += __shfl_xor(v, 2, 16);
    v += __shfl_xor(v, 4, 16);
    v += __shfl_xor(v, 8, 16);
    return v;
}
__device__ __forceinline__ float gmax16(float v) {
    v = fmaxf(v, __shfl_xor(v, 1, 16));
    v = fmaxf(v, __shfl_xor(v, 2, 16));
    v = fmaxf(v, __shfl_xor(v, 4, 16));
    v = fmaxf(v, __shfl_xor(v, 8, 16));
    return v;
}

template <int K>
__device__ __forceinline__ int rotk(int x) {
    return __builtin_amdgcn_mov_dpp(x, 0x120 + K, 0xF, 0xF, true);
}

// One HMM step, rotated-W layout, PACKED fp32 (r9-proven v_pk_* form).
// Takes current colsum T, returns new colsum. Renorm lives outside.
__device__ __forceinline__ float step2(v2f (&Wv)[8], float T, float xx,
                                       float A2, float B2, float C2) {
    const float amb = 0.9f - 0.1f / 15.0f;
    const float bco = 0.1f / 15.0f;
    float myl = fexp2(fmaf(xx, fmaf(xx, A2, B2), C2));   // ONE exp per lane
    int mi = __float_as_int(myl);
    float bT = bco * T;
    v2f bT2 = {bT, bT};
    v2f amb2 = {amb, amb};
    v2f L0 = {myl,                          __int_as_float(rotk<1>(mi))};
    v2f L1 = {__int_as_float(rotk<2>(mi)),  __int_as_float(rotk<3>(mi))};
    v2f L2 = {__int_as_float(rotk<4>(mi)),  __int_as_float(rotk<5>(mi))};
    v2f L3 = {__int_as_float(rotk<6>(mi)),  __int_as_float(rotk<7>(mi))};
    v2f L4 = {__int_as_float(rotk<8>(mi)),  __int_as_float(rotk<9>(mi))};
    v2f L5 = {__int_as_float(rotk<10>(mi)), __int_as_float(rotk<11>(mi))};
    v2f L6 = {__int_as_float(rotk<12>(mi)), __int_as_float(rotk<13>(mi))};
    v2f L7 = {__int_as_float(rotk<14>(mi)), __int_as_float(rotk<15>(mi))};
    Wv[0] = __builtin_elementwise_fma(amb2, Wv[0], bT2) * L0;
    Wv[1] = __builtin_elementwise_fma(amb2, Wv[1], bT2) * L1;
    Wv[2] = __builtin_elementwise_fma(amb2, Wv[2], bT2) * L2;
    Wv[3] = __builtin_elementwise_fma(amb2, Wv[3], bT2) * L3;
    Wv[4] = __builtin_elementwise_fma(amb2, Wv[4], bT2) * L4;
    Wv[5] = __builtin_elementwise_fma(amb2, Wv[5], bT2) * L5;
    Wv[6] = __builtin_elementwise_fma(amb2, Wv[6], bT2) * L6;
    Wv[7] = __builtin_elementwise_fma(amb2, Wv[7], bT2) * L7;
    v2f s = ((Wv[0] + Wv[1]) + (Wv[2] + Wv[3])) + ((Wv[4] + Wv[5]) + (Wv[6] + Wv[7]));
    return s.x + s.y;
}

// Renormalized product of two LDS R-only units: C = Mb * Ma (b = later chunk).
// B rows read contiguous (float4); A columns read strided float2 (8-way lane
// broadcast per address, 16 consecutive words per k -> conflict-free).
// INVARIANT: output is max-colsum-normalized; log2 scale accumulates in pad.
__device__ __forceinline__ void combineUnits(float* lds, int ua, int ub, int ud, int lane) {
    const float* MbR = lds + ub * UNIT;
    const float* MaR = lds + ua * UNIT;
    float mxa = lds[ua * UNIT + 16];
    float mxb = lds[ub * UNIT + 16];
    int a = lane >> 3, cc = lane & 7;
    float b0[16], b1[16];
    const float4* pb0 = (const float4*)(MbR + (2 * a) * ROWS);
    const float4* pb1 = (const float4*)(MbR + (2 * a + 1) * ROWS);
#pragma unroll
    for (int q = 0; q < 4; ++q) {
        *(float4*)&b0[4 * q] = pb0[q];
        *(float4*)&b1[4 * q] = pb1[q];
    }
    float c00 = 0.f, c01 = 0.f, c10 = 0.f, c11 = 0.f;
#pragma unroll
    for (int k = 0; k < 16; ++k) {
        float2 av = *(const float2*)(MaR + k * ROWS + 2 * cc);
        c00 = fmaf(b0[k], av.x, c00);
        c01 = fmaf(b0[k], av.y, c01);
        c10 = fmaf(b1[k], av.x, c10);
        c11 = fmaf(b1[k], av.y, c11);
    }
    float cs0 = c00 + c10;
    float cs1 = c01 + c11;
    cs0 += __shfl_xor(cs0, 8);  cs1 += __shfl_xor(cs1, 8);
    cs0 += __shfl_xor(cs0, 16); cs1 += __shfl_xor(cs1, 16);
    cs0 += __shfl_xor(cs0, 32); cs1 += __shfl_xor(cs1, 32);
    float mxc = fmaxf(cs0, cs1);
    mxc = fmaxf(mxc, __shfl_xor(mxc, 1));
    mxc = fmaxf(mxc, __shfl_xor(mxc, 2));
    mxc = fmaxf(mxc, __shfl_xor(mxc, 4));
    float is = 1.0f / mxc;
    c00 *= is; c01 *= is; c10 *= is; c11 *= is;
    float* dR = lds + ud * UNIT;
    *(float2*)(dR + (2 * a) * ROWS + 2 * cc)     = make_float2(c00, c01);
    *(float2*)(dR + (2 * a + 1) * ROWS + 2 * cc) = make_float2(c10, c11);
    if (lane == 0) lds[ud * UNIT + 16] = mxa + mxb + flog2(mxc);
}

// Phase 1: thread (b, chunk c, column r) evolves basis e_r through a 32-step
// chunk; block tree-combines its 16 chunks 16->1 with per-level renorm
// (INVARIANT: every stored/combined matrix is max-colsum-normalized).
// 32-step chunks double total threads (524,288 -> up to 8 waves/SIMD) vs the
// r13 64-step layout whose 262,144 threads capped occupancy at 4 waves/SIMD.
// LDS 20,480 B + launch_bounds(256,6) -> 6-7 blocks/CU resident.
// NO single-kernel fusion: device-scope fences flush per-XCD L2 on gfx950 —
// r14's fused version ran 5x slower.
__global__ __launch_bounds__(256, 6) void hmm_phase1(const float* __restrict__ obvs,
                                                     const float* __restrict__ mu,
                                                     const float* __restrict__ log_sigma,
                                                     float* __restrict__ wsW,
                                                     float* __restrict__ wsM,
                                                     float* __restrict__ out) {
    __shared__ float lds[16 * UNIT];       // 16 R-units, 20,480 B
    int tid = blockIdx.x * 256 + threadIdx.x;
    if (tid == 0) out[0] = 0.0f;           // phase23 atomicAdds after this dispatch
    int r = threadIdx.x & 15;
    int u = threadIdx.x >> 4;              // local chunk 0..15
    int g = tid >> 4;                      // g = b*NC + c
    int b = g >> 8;                        // NC = 256
    int c = g & (NC - 1);

    float ls = log_sigma[r];
    float mk = mu[r];
    float iv = fexp2(-2.0f * LOG2E * ls);
    float A2 = -0.5f * LOG2E * iv;
    float B2 = LOG2E * mk * iv;
    float C2 = LOG2E * (-0.5f * mk * mk * iv - ls - HLOG2PI);

    v2f Wv[8];
#pragma unroll
    for (int i = 0; i < 8; ++i) Wv[i] = (v2f){0.0f, 0.0f};
    Wv[0].x = 1.0f;                        // identity in rotated layout
    int ilog = 0;
    float T = 1.0f;

    const float4* ob4 = (const float4*)(obvs + (long)b * NS) + c * M4;
    float4 xv = ob4[0];
    float4 xn = ob4[1];
    // peeled m=0 group: chunk 0 skips t=0 (handled as init vector in phase23)
    if (c) T = step2(Wv, T, xv.x, A2, B2, C2);
    T = step2(Wv, T, xv.y, A2, B2, C2);
    T = step2(Wv, T, xv.z, A2, B2, C2);
    T = step2(Wv, T, xv.w, A2, B2, C2);
    {
        int te = (__float_as_int(T) >> 23) & 255;
        int ok = (te != 0);
        float s = ok ? __int_as_float((254 - te) << 23) : 1.0f;
        ilog += ok ? (te - 127) : 0;
        v2f s2 = {s, s};
#pragma unroll
        for (int i = 0; i < 8; ++i) Wv[i] *= s2;
        T *= s;
    }
    xv = xn;
    for (int m = 1; m < M4; ++m) {
        xn = ob4[(m + 1) < M4 ? (m + 1) : m];
        T = step2(Wv, T, xv.x, A2, B2, C2);
        T = step2(Wv, T, xv.y, A2, B2, C2);
        T = step2(Wv, T, xv.z, A2, B2, C2);
        T = step2(Wv, T, xv.w, A2, B2, C2);
        // guarded branchless exponent renorm (r8/9/11/12/13-proven)
        int te = (__float_as_int(T) >> 23) & 255;
        int ok = (te != 0);
        float s = ok ? __int_as_float((254 - te) << 23) : 1.0f;
        ilog += ok ? (te - 127) : 0;
        v2f s2 = {s, s};
#pragma unroll
        for (int i = 0; i < 8; ++i) Wv[i] *= s2;
        T *= s;
        xv = xn;
    }

    float lg = (float)ilog + flog2(T);     // true column log2-sum (T in [1,2))
    float mx = gmax16(lg);                 // chunk max over 16 columns
    float sc = fexp2((float)ilog - mx);    // scale so chunk max colsum = 1

    // normalized chunk matrix into LDS R layout; sid[K] == (r+K)&15 computed
    // arithmetically (no rotk / no 16-reg array — keeps VGPR under the cap)
    float* Ru = lds + u * UNIT;
#pragma unroll
    for (int i = 0; i < 8; ++i) {
        int j0 = (r + 2 * i) & 15;
        int j1 = (r + 2 * i + 1) & 15;
        Ru[j0 * ROWS + r] = Wv[i].x * sc;
        Ru[j1 * ROWS + r] = Wv[i].y * sc;
    }
    if (r == 0) Ru[16] = mx;
    __syncthreads();

    // in-LDS renormalized tree 16 -> 8 -> 4 -> 2 -> 1 (r13-proven structure)
    int lane = threadIdx.x & 63;
    int wid = threadIdx.x >> 6;
#pragma unroll
    for (int q = 0; q < 2; ++q) {
        int p = 2 * wid + q;
        combineUnits(lds, 2 * p, 2 * p + 1, 2 * p, lane);
    }
    __syncthreads();
    if (wid < 4) combineUnits(lds, 4 * wid, 4 * wid + 2, 4 * wid, lane);
    __syncthreads();
    if (wid < 2) combineUnits(lds, 8 * wid, 8 * wid + 4, 8 * wid, lane);
    __syncthreads();
    if (wid == 0) combineUnits(lds, 0, 8, 0, lane);
    __syncthreads();

    // emit: one matrix per block in [j][r] layout + its log2-scale
    wsW[(long)blockIdx.x * 256 + threadIdx.x] =
        lds[(threadIdx.x >> 4) * ROWS + (threadIdx.x & 15)];
    if (threadIdx.x == 0) wsM[blockIdx.x] = lds[16];
}

// Phase 2+3: stage 16 matrices per sequence, run the SAME renormalizing
// 16->1 tree as phase1 (4 renormed levels — safer than r13's 3 unnormalized),
// then the t=0 init-vector epilogue. Tree log2-scale (lds[16]) joins msum.
__global__ __launch_bounds__(256, 2) void hmm_phase23(const float* __restrict__ obvs,
                                                      const float* __restrict__ mu,
                                                      const float* __restrict__ log_sigma,
                                                      const float* __restrict__ prior_logits,
                                                      const float* __restrict__ wsW,
                                                      const float* __restrict__ wsM,
                                                      float* __restrict__ out) {
    __shared__ float lds[16 * UNIT];       // 20,480 B
    int bb = blockIdx.x;
    int tid = threadIdx.x;
    int wid = tid >> 6;
    int lane = tid & 63;

    // stage 16 matrices in R layout (4096 floats = 4 float4 per thread)
    const float4* src = (const float4*)(wsW + (long)bb * NCP * 256);
#pragma unroll
    for (int q = 0; q < 4; ++q) {
        int f = tid + q * 256;
        float4 v = src[f];
        int m = f >> 6, idx = f & 63, j = idx >> 2, kq = idx & 3;
        *(float4*)(lds + m * UNIT + j * ROWS + kq * 4) = v;
    }
    if (tid < 16) lds[tid * UNIT + 16] = 0.0f;   // inputs carry no LDS scale
    __syncthreads();

#pragma unroll
    for (int q = 0; q < 2; ++q) {
        int p = 2 * wid + q;
        combineUnits(lds, 2 * p, 2 * p + 1, 2 * p, lane);
    }
    __syncthreads();
    if (wid < 4) combineUnits(lds, 4 * wid, 4 * wid + 2, 4 * wid, lane);
    __syncthreads();
    if (wid < 2) combineUnits(lds, 8 * wid, 8 * wid + 4, 8 * wid, lane);
    __syncthreads();
    if (wid == 0) combineUnits(lds, 0, 8, 0, lane);
    __syncthreads();
    // final combined matrix rows at lds[j*ROWS + k], tree scale at lds[16]

    if (tid < 16) {
        int jj = tid;
        float ls = log_sigma[jj];
        float mk = mu[jj];
        float iv = fexp2(-2.0f * LOG2E * ls);
        float A2 = -0.5f * LOG2E * iv;
        float B2 = LOG2E * mk * iv;
        float C2 = LOG2E * (-0.5f * mk * mk * iv - ls - HLOG2PI);
        float x = obvs[(long)bb * NS];                   // t = 0
        float e = fexp2(LOG2E * prior_logits[jj]);
        float Z = gsum16(e);
        float p0 = fexp2(fmaf(x, fmaf(x, A2, B2), C2)) * e;
        const float* Mrow = lds + jj * ROWS;
        float mr[16];
        *(float4*)&mr[0]  = ((const float4*)Mrow)[0];
        *(float4*)&mr[4]  = ((const float4*)Mrow)[1];
        *(float4*)&mr[8]  = ((const float4*)Mrow)[2];
        *(float4*)&mr[12] = ((const float4*)Mrow)[3];
        float q = 0.0f;
#pragma unroll
        for (int rr = 0; rr < 16; ++rr) q = fmaf(mr[rr], __shfl(p0, rr, 16), q);
        float Tq = gsum16(q);
        float pm = wsM[bb * NCP + jj];                   // all 16 block scales
        float msum = gsum16(pm);
        if (jj == 0) {
            float res = (flog2(Tq) + lds[16] - flog2(Z) + msum) * LN2;
            atomicAdd(out, res);
        }
    }
}

extern "C" void kernel_launch(void* const* d_in, const int* in_sizes, int n_in,
                              void* d_out, int out_size, void* d_ws, size_t ws_size,
                              hipStream_t stream) {
    const float* obvs = (const float*)d_in[0];
    const float* mu = (const float*)d_in[1];
    const float* log_sigma = (const float*)d_in[2];
    const float* prior_logits = (const float*)d_in[3];
    float* out = (float*)d_out;

    float* wsW = (float*)d_ws;                          // NB*NCP*256 floats = 2.1 MB
    float* wsM = wsW + (size_t)NB * NCP * 256;          // NB*NCP floats

    hmm_phase1<<<dim3(NB * NC * 16 / 256), dim3(256), 0, stream>>>(obvs, mu, log_sigma,
                                                                   wsW, wsM, out);
    hmm_phase23<<<dim3(NB), dim3(256), 0, stream>>>(obvs, mu, log_sigma, prior_logits,
                                                    wsW, wsM, out);
}

// Round 2
// 92.546 us; speedup vs baseline: 1.0352x; 1.0352x over previous
//
#include <hip/hip_runtime.h>

#define NB 128
#define NS 8192
#define NC 128                // chunks per sequence (64-step chunks; r0-proven geometry)
#define NCP 8                 // combined matrices per sequence (one per block)
#define NL (NS / NC)          // 64 steps per chunk
#define M4 (NL / 4)           // 16 float4 groups

#define LOG2E 1.4426950408889634f
#define HLOG2PI 0.918938533204672742f
#define LN2 0.69314718055994531f

// LDS matrix layout: R-only units (r1-proven). Transposed operand in combine
// is read strided (8-way broadcast float2 reads -> conflict-free). mx scale
// lives in row-0 pad (col 16).
#define ROWS 20          // padded leading dim
#define UNIT 320         // one unit: R[16x20]

__device__ __forceinline__ float fexp2(float x) { return __builtin_amdgcn_exp2f(x); }
__device__ __forceinline__ float flog2(float x) { return __builtin_amdgcn_logf(x); }

__device__ __forceinline__ float gsum16(float v) {
    v += __shfl_xor(v, 1, 16);
    v += __shfl_xor(v, 2, 16);
    v += __shfl_xor(v, 4, 16);
    v += __shfl_xor(v, 8, 16);
    return v;
}
__device__ __forceinline__ float gmax16(float v) {
    v = fmaxf(v, __shfl_xor(v, 1, 16));
    v = fmaxf(v, __shfl_xor(v, 2, 16));
    v = fmaxf(v, __shfl_xor(v, 4, 16));
    v = fmaxf(v, __shfl_xor(v, 8, 16));
    return v;
}

// Fused broadcast-multiply: W *= rot_k(mylg) in ONE VOP2+DPP instruction
// (replaces v_mov_b32_dpp + v_mul pairs). DPP operand is src0; src1/dst = W.
// mylg is produced by a guarded mov (s_nop 1 covers the 2-wait-state
// VALU-write -> DPP-read hazard; W as src1 uses the normal read port, no hazard).
#define MULROT(w, K)                                                            \
    asm("v_mul_f32_dpp %0, %1, %0 row_ror:" #K " row_mask:0xf bank_mask:0xf"    \
        : "+v"(w) : "v"(mylg))

// One HMM step, rotated-W layout, SCALAR form with fused DPP muls.
// W[k] = column entry for row (r+k)&15. Takes colsum T, returns new colsum.
__device__ __forceinline__ float stepS(float (&W)[16], float T, float xx,
                                       float A2, float B2, float C2) {
    const float amb = 0.9f - 0.1f / 15.0f;
    const float bco = 0.1f / 15.0f;
    float myl = fexp2(fmaf(xx, fmaf(xx, A2, B2), C2));   // ONE exp per lane
    float bT = bco * T;
    float mylg;
    asm("v_mov_b32 %0, %1\n\ts_nop 1" : "=v"(mylg) : "v"(myl));
#pragma unroll
    for (int k = 0; k < 16; ++k) W[k] = fmaf(amb, W[k], bT);
    W[0] *= myl;
    MULROT(W[1], 1);   MULROT(W[2], 2);   MULROT(W[3], 3);
    MULROT(W[4], 4);   MULROT(W[5], 5);   MULROT(W[6], 6);
    MULROT(W[7], 7);   MULROT(W[8], 8);   MULROT(W[9], 9);
    MULROT(W[10], 10); MULROT(W[11], 11); MULROT(W[12], 12);
    MULROT(W[13], 13); MULROT(W[14], 14); MULROT(W[15], 15);
    float a0 = W[0] + W[1],   a1 = W[2] + W[3];
    float a2 = W[4] + W[5],   a3 = W[6] + W[7];
    float a4 = W[8] + W[9],   a5 = W[10] + W[11];
    float a6 = W[12] + W[13], a7 = W[14] + W[15];
    float b0 = a0 + a1, b1 = a2 + a3, b2 = a4 + a5, b3 = a6 + a7;
    return (b0 + b1) + (b2 + b3);
}

// Renormalized product of two LDS R-only units: C = Mb * Ma (b = later chunk).
// B rows read contiguous (float4); A columns read strided float2 (8-way lane
// broadcast per address -> conflict-free). INVARIANT: output is
// max-colsum-normalized; log2 scale accumulates in pad.
__device__ __forceinline__ void combineUnits(float* lds, int ua, int ub, int ud, int lane) {
    const float* MbR = lds + ub * UNIT;
    const float* MaR = lds + ua * UNIT;
    float mxa = lds[ua * UNIT + 16];
    float mxb = lds[ub * UNIT + 16];
    int a = lane >> 3, cc = lane & 7;
    float b0[16], b1[16];
    const float4* pb0 = (const float4*)(MbR + (2 * a) * ROWS);
    const float4* pb1 = (const float4*)(MbR + (2 * a + 1) * ROWS);
#pragma unroll
    for (int q = 0; q < 4; ++q) {
        *(float4*)&b0[4 * q] = pb0[q];
        *(float4*)&b1[4 * q] = pb1[q];
    }
    float c00 = 0.f, c01 = 0.f, c10 = 0.f, c11 = 0.f;
#pragma unroll
    for (int k = 0; k < 16; ++k) {
        float2 av = *(const float2*)(MaR + k * ROWS + 2 * cc);
        c00 = fmaf(b0[k], av.x, c00);
        c01 = fmaf(b0[k], av.y, c01);
        c10 = fmaf(b1[k], av.x, c10);
        c11 = fmaf(b1[k], av.y, c11);
    }
    float cs0 = c00 + c10;
    float cs1 = c01 + c11;
    cs0 += __shfl_xor(cs0, 8);  cs1 += __shfl_xor(cs1, 8);
    cs0 += __shfl_xor(cs0, 16); cs1 += __shfl_xor(cs1, 16);
    cs0 += __shfl_xor(cs0, 32); cs1 += __shfl_xor(cs1, 32);
    float mxc = fmaxf(cs0, cs1);
    mxc = fmaxf(mxc, __shfl_xor(mxc, 1));
    mxc = fmaxf(mxc, __shfl_xor(mxc, 2));
    mxc = fmaxf(mxc, __shfl_xor(mxc, 4));
    float is = 1.0f / mxc;
    c00 *= is; c01 *= is; c10 *= is; c11 *= is;
    float* dR = lds + ud * UNIT;
    *(float2*)(dR + (2 * a) * ROWS + 2 * cc)     = make_float2(c00, c01);
    *(float2*)(dR + (2 * a + 1) * ROWS + 2 * cc) = make_float2(c10, c11);
    if (lane == 0) lds[ud * UNIT + 16] = mxa + mxb + flog2(mxc);
}

// Phase 1: thread (b, chunk c, column r) evolves basis e_r through a 64-step
// chunk; block tree-combines its 16 chunks 16->1 with per-level renorm
// (INVARIANT: every stored/combined matrix is max-colsum-normalized).
// Geometry reverted to r0 (64-step chunks): R1 showed the loop is issue-bound,
// not occupancy-bound — doubling waves/SIMD only added tree overhead (+3us).
// NO single-kernel fusion: device-scope fences flush per-XCD L2 on gfx950 —
// the fused variant ran 5x slower.
__global__ __launch_bounds__(256, 4) void hmm_phase1(const float* __restrict__ obvs,
                                                     const float* __restrict__ mu,
                                                     const float* __restrict__ log_sigma,
                                                     float* __restrict__ wsW,
                                                     float* __restrict__ wsM,
                                                     float* __restrict__ out) {
    __shared__ float lds[16 * UNIT];       // 16 R-units, 20,480 B
    int tid = blockIdx.x * 256 + threadIdx.x;
    if (tid == 0) out[0] = 0.0f;           // phase23 atomicAdds after this dispatch
    int r = threadIdx.x & 15;
    int u = threadIdx.x >> 4;              // local chunk 0..15
    int g = tid >> 4;                      // g = b*NC + c
    int b = g >> 7;                        // NC = 128
    int c = g & (NC - 1);

    float ls = log_sigma[r];
    float mk = mu[r];
    float iv = fexp2(-2.0f * LOG2E * ls);
    float A2 = -0.5f * LOG2E * iv;
    float B2 = LOG2E * mk * iv;
    float C2 = LOG2E * (-0.5f * mk * mk * iv - ls - HLOG2PI);

    float W[16];
#pragma unroll
    for (int i = 0; i < 16; ++i) W[i] = 0.0f;
    W[0] = 1.0f;                           // identity in rotated layout
    int ilog = 0;
    float T = 1.0f;

    const float4* ob4 = (const float4*)(obvs + (long)b * NS) + c * M4;
    float4 xv = ob4[0];
    float4 xn = ob4[1];
    // peeled m=0 group: chunk 0 skips t=0 (handled as init vector in phase23)
    if (c) T = stepS(W, T, xv.x, A2, B2, C2);
    T = stepS(W, T, xv.y, A2, B2, C2);
    T = stepS(W, T, xv.z, A2, B2, C2);
    T = stepS(W, T, xv.w, A2, B2, C2);
    {
        int te = (__float_as_int(T) >> 23) & 255;
        int ok = (te != 0);
        float s = ok ? __int_as_float((254 - te) << 23) : 1.0f;
        ilog += ok ? (te - 127) : 0;
#pragma unroll
        for (int i = 0; i < 16; ++i) W[i] *= s;
        T *= s;
    }
    xv = xn;
    for (int m = 1; m < M4; ++m) {
        xn = ob4[(m + 1) < M4 ? (m + 1) : m];
        T = stepS(W, T, xv.x, A2, B2, C2);
        T = stepS(W, T, xv.y, A2, B2, C2);
        T = stepS(W, T, xv.z, A2, B2, C2);
        T = stepS(W, T, xv.w, A2, B2, C2);
        // guarded branchless exponent renorm (proven)
        int te = (__float_as_int(T) >> 23) & 255;
        int ok = (te != 0);
        float s = ok ? __int_as_float((254 - te) << 23) : 1.0f;
        ilog += ok ? (te - 127) : 0;
#pragma unroll
        for (int i = 0; i < 16; ++i) W[i] *= s;
        T *= s;
        xv = xn;
    }

    float lg = (float)ilog + flog2(T);     // true column log2-sum (T in [1,2))
    float mx = gmax16(lg);                 // chunk max over 16 columns
    float sc = fexp2((float)ilog - mx);    // scale so chunk max colsum = 1

    // normalized chunk matrix into LDS R layout; row of W[k] is (r+k)&15
    float* Ru = lds + u * UNIT;
#pragma unroll
    for (int k = 0; k < 16; ++k) {
        int j = (r + k) & 15;
        Ru[j * ROWS + r] = W[k] * sc;
    }
    if (r == 0) Ru[16] = mx;
    __syncthreads();

    // in-LDS renormalized tree 16 -> 8 -> 4 -> 2 -> 1 (proven structure)
    int lane = threadIdx.x & 63;
    int wid = threadIdx.x >> 6;
#pragma unroll
    for (int q = 0; q < 2; ++q) {
        int p = 2 * wid + q;
        combineUnits(lds, 2 * p, 2 * p + 1, 2 * p, lane);
    }
    __syncthreads();
    if (wid < 4) combineUnits(lds, 4 * wid, 4 * wid + 2, 4 * wid, lane);
    __syncthreads();
    if (wid < 2) combineUnits(lds, 8 * wid, 8 * wid + 4, 8 * wid, lane);
    __syncthreads();
    if (wid == 0) combineUnits(lds, 0, 8, 0, lane);
    __syncthreads();

    // emit: one matrix per block in [j][r] layout + its log2-scale
    wsW[(long)blockIdx.x * 256 + threadIdx.x] =
        lds[(threadIdx.x >> 4) * ROWS + (threadIdx.x & 15)];
    if (threadIdx.x == 0) wsM[blockIdx.x] = lds[16];
}

// Phase 2+3: stage 8 matrices per sequence, renormalizing 8->1 tree
// (3 renormed levels), then the t=0 init-vector epilogue. Tree log2-scale
// (lds[16]) joins msum.
__global__ __launch_bounds__(256, 2) void hmm_phase23(const float* __restrict__ obvs,
                                                      const float* __restrict__ mu,
                                                      const float* __restrict__ log_sigma,
                                                      const float* __restrict__ prior_logits,
                                                      const float* __restrict__ wsW,
                                                      const float* __restrict__ wsM,
                                                      float* __restrict__ out) {
    __shared__ float lds[16 * UNIT];       // 20,480 B (8 units used)
    int bb = blockIdx.x;
    int tid = threadIdx.x;
    int wid = tid >> 6;
    int lane = tid & 63;

    // stage 8 matrices in R layout (2048 floats = 2 float4 per thread)
    const float4* src = (const float4*)(wsW + (long)bb * NCP * 256);
#pragma unroll
    for (int q = 0; q < 2; ++q) {
        int f = tid + q * 256;
        float4 v = src[f];
        int m = f >> 6, idx = f & 63, j = idx >> 2, kq = idx & 3;
        *(float4*)(lds + m * UNIT + j * ROWS + kq * 4) = v;
    }
    if (tid < NCP) lds[tid * UNIT + 16] = 0.0f;   // inputs carry no LDS scale
    __syncthreads();

    // tree 8 -> 4 -> 2 -> 1 (later * earlier), renormed at every level
    if (wid < 4) combineUnits(lds, 2 * wid, 2 * wid + 1, 2 * wid, lane);
    __syncthreads();
    if (wid < 2) combineUnits(lds, 4 * wid, 4 * wid + 2, 4 * wid, lane);
    __syncthreads();
    if (wid == 0) combineUnits(lds, 0, 4, 0, lane);
    __syncthreads();
    // final combined matrix rows at lds[j*ROWS + k], tree scale at lds[16]

    if (tid < 16) {
        int jj = tid;
        float ls = log_sigma[jj];
        float mk = mu[jj];
        float iv = fexp2(-2.0f * LOG2E * ls);
        float A2 = -0.5f * LOG2E * iv;
        float B2 = LOG2E * mk * iv;
        float C2 = LOG2E * (-0.5f * mk * mk * iv - ls - HLOG2PI);
        float x = obvs[(long)bb * NS];                   // t = 0
        float e = fexp2(LOG2E * prior_logits[jj]);
        float Z = gsum16(e);
        float p0 = fexp2(fmaf(x, fmaf(x, A2, B2), C2)) * e;
        const float* Mrow = lds + jj * ROWS;
        float mr[16];
        *(float4*)&mr[0]  = ((const float4*)Mrow)[0];
        *(float4*)&mr[4]  = ((const float4*)Mrow)[1];
        *(float4*)&mr[8]  = ((const float4*)Mrow)[2];
        *(float4*)&mr[12] = ((const float4*)Mrow)[3];
        float q = 0.0f;
#pragma unroll
        for (int rr = 0; rr < 16; ++rr) q = fmaf(mr[rr], __shfl(p0, rr, 16), q);
        float Tq = gsum16(q);
        float pm = (jj < NCP) ? wsM[bb * NCP + jj] : 0.0f;
        float msum = gsum16(pm);
        if (jj == 0) {
            float res = (flog2(Tq) + lds[16] - flog2(Z) + msum) * LN2;
            atomicAdd(out, res);
        }
    }
}

extern "C" void kernel_launch(void* const* d_in, const int* in_sizes, int n_in,
                              void* d_out, int out_size, void* d_ws, size_t ws_size,
                              hipStream_t stream) {
    const float* obvs = (const float*)d_in[0];
    const float* mu = (const float*)d_in[1];
    const float* log_sigma = (const float*)d_in[2];
    const float* prior_logits = (const float*)d_in[3];
    float* out = (float*)d_out;

    float* wsW = (float*)d_ws;                          // NB*NCP*256 floats = 1.05 MB
    float* wsM = wsW + (size_t)NB * NCP * 256;          // NB*NCP floats

    hmm_phase1<<<dim3(NB * NC * 16 / 256), dim3(256), 0, stream>>>(obvs, mu, log_sigma,
                                                                   wsW, wsM, out);
    hmm_phase23<<<dim3(NB), dim3(256), 0, stream>>>(obvs, mu, log_sigma, prior_logits,
                                                    wsW, wsM, out);
}